// Round 18
// baseline (327.074 us; speedup 1.0000x reference)
//
#include <hip/hip_runtime.h>
#include <hip/hip_fp16.h>

#define NFEAT 16
#define D 32
#define NB 64        // num graphs
#define TCOLS 2080   // 65*32
#define CHUNK 16     // nodes per fused block (phase-A MFMA rows fully used)
#define CPAD 16      // counter padding: one counter per 64B line
#define KBN 16       // nodes per kB block

static inline size_t align_up(size_t x, size_t a){ return (x + a - 1) & ~(a - 1); }

typedef _Float16 f16x2 __attribute__((ext_vector_type(2)));
typedef _Float16 f16x8 __attribute__((ext_vector_type(8)));
typedef float f32x4 __attribute__((ext_vector_type(4)));

__device__ inline unsigned int pk2(float a, float b){
  __half2 h = __floats2half2_rn(a, b);
  union { __half2 h; unsigned int u; } cv; cv.h = h; return cv.u;
}

__device__ inline float dot2(unsigned int a, unsigned int b, float c){
  union { unsigned int u; f16x2 h; } ua, ub; ua.u = a; ub.u = b;
#if __has_builtin(__builtin_amdgcn_fdot2)
  return __builtin_amdgcn_fdot2(ua.h, ub.h, c, false);
#else
  return c + (float)ua.h[0] * (float)ub.h[0] + (float)ua.h[1] * (float)ub.h[1];
#endif
}

// ---------- setup kernels ----------

// B-fragment layout for v_mfma_f32_16x16x32_f16 (tile c: cols c*16..+15, col=h*32+o)
__global__ __launch_bounds__(256) void kBuildMpk2(const float* __restrict__ w2,
                                                  const float* __restrict__ b2,
                                                  unsigned int* __restrict__ Mpk2){
  int idx = blockIdx.x * 256 + threadIdx.x;
  if (idx >= 130 * 64 * 4) return;
  int j2 = idx & 3;
  int l  = (idx >> 2) & 63;
  int c  = idx >> 8;
  int col = c * 16 + (l & 15);
  int h = col >> 5, o = col & 31;
  int ke = (l >> 4) * 8 + 2 * j2;
  float f0, f1;
  if (h < 64){
    f0 = w2[h * 1024 + ke * 32 + o];
    f1 = w2[h * 1024 + (ke + 1) * 32 + o];
  } else {
    f0 = b2[ke * 32 + o];
    f1 = b2[(ke + 1) * 32 + o];
  }
  Mpk2[idx] = pk2(f0, f1);
}

__global__ __launch_bounds__(256) void kLin0(const float* __restrict__ x,
                                             const float* __restrict__ w,
                                             const float* __restrict__ b,
                                             float* __restrict__ feat, int N){
  int idx = blockIdx.x * 256 + threadIdx.x;
  int u = idx >> 5, o = idx & 31;
  if (u >= N) return;
  float acc = b[o];
#pragma unroll
  for (int i = 0; i < NFEAT; i++) acc += x[(size_t)u * NFEAT + i] * w[i * 32 + o];
  feat[idx] = fmaxf(acc, 0.f);
}

// counts (padded) + ranks in one pass
__global__ __launch_bounds__(256) void kCountRank(const int* __restrict__ ei,
                                                  int* __restrict__ cnt_src,
                                                  int* __restrict__ cnt_dst,
                                                  int* __restrict__ rs,
                                                  int* __restrict__ rd, int E){
  int e = blockIdx.x * 256 + threadIdx.x;
  if (e >= E) return;
  int s = ei[e], d = ei[E + e];
  rs[e] = atomicAdd(&cnt_src[(size_t)s * CPAD], 1);
  rd[e] = atomicAdd(&cnt_dst[(size_t)d * CPAD], 1);
}

// hierarchical scan, stage A: per-256-tile block scan; grid (NT, 2)
__global__ __launch_bounds__(256) void kScanA(const int* __restrict__ cnt_src,
                                              const int* __restrict__ cnt_dst,
                                              int* __restrict__ src_off,
                                              int* __restrict__ dst_off,
                                              int* __restrict__ bsum,
                                              float* __restrict__ deg,
                                              int N, int NT){
  int y = blockIdx.y;
  const int* cnt = y ? cnt_dst : cnt_src;
  int* off = y ? dst_off : src_off;
  int t = threadIdx.x;
  int i = blockIdx.x * 256 + t;
  int c = (i < N) ? cnt[(size_t)i * CPAD] : 0;
  if (y && i < N) deg[i] = (float)max(c, 1);
  __shared__ int sh[256];
  sh[t] = c; __syncthreads();
  for (int d = 1; d < 256; d <<= 1){
    int v = (t >= d) ? sh[t - d] : 0;
    __syncthreads();
    sh[t] += v;
    __syncthreads();
  }
  if (i < N) off[i] = sh[t] - c;           // within-tile exclusive
  if (t == 255) bsum[y * NT + blockIdx.x] = sh[255];
}

// stage B: scan tile sums (NT<=256) + batch offsets via bsearch
__global__ __launch_bounds__(256) void kScanB(int* __restrict__ bsum,
                                              const int* __restrict__ batch,
                                              int* __restrict__ boff,
                                              int* __restrict__ src_off,
                                              int* __restrict__ dst_off,
                                              int N, int NT, int B, int E){
  int t = threadIdx.x;
  __shared__ int sh[256];
  for (int y = 0; y < 2; y++){
    int v = (t < NT) ? bsum[y * NT + t] : 0;
    sh[t] = v; __syncthreads();
    for (int d = 1; d < 256; d <<= 1){
      int u = (t >= d) ? sh[t - d] : 0;
      __syncthreads();
      sh[t] += u;
      __syncthreads();
    }
    if (t < NT) bsum[y * NT + t] = sh[t] - v;   // exclusive tile offset
    __syncthreads();
  }
  if (t <= B){
    int lo = 0, hi = N;
    while (lo < hi){ int mid = (lo + hi) >> 1; if (batch[mid] < t) lo = mid + 1; else hi = mid; }
    boff[t] = lo;
  }
  if (t == 0){ src_off[N] = E; dst_off[N] = E; }
}

// stage C: add tile offsets; grid (NT, 2)
__global__ __launch_bounds__(256) void kScanC(int* __restrict__ src_off,
                                              int* __restrict__ dst_off,
                                              const int* __restrict__ bsum,
                                              int N, int NT){
  int y = blockIdx.y;
  int i = blockIdx.x * 256 + threadIdx.x;
  if (i < N) (y ? dst_off : src_off)[i] += bsum[y * NT + blockIdx.x];
}

// fused placement + edge MLP: edge e (original order), 32 lanes per edge.
// writes apk row at src-CSR position ps (128B-contiguous scatter) and s2d.
__global__ __launch_bounds__(256) void kEdgeMLPpk(const float* __restrict__ ea,
                                                  const float* __restrict__ w1,
                                                  const float* __restrict__ b1,
                                                  const int* __restrict__ ei,
                                                  const int* __restrict__ src_off,
                                                  const int* __restrict__ dst_off,
                                                  const int* __restrict__ rs,
                                                  const int* __restrict__ rd,
                                                  unsigned int* __restrict__ apk,
                                                  int* __restrict__ s2d, int E){
  int idx = blockIdx.x * 256 + threadIdx.x;
  int e = idx >> 5, h2 = idx & 31;
  if (e >= E) return;
  int s = ei[e], d = ei[E + e];
  int ps = src_off[s] + rs[e];
  const float* eap = ea + (size_t)e * 5;
  float q0 = eap[0], q1 = eap[1], q2 = eap[2], q3 = eap[3], q4 = eap[4];
  int h = 2 * h2;
  float lo = b1[h]     + q0 * w1[h]       + q1 * w1[64 + h]     + q2 * w1[128 + h]
                       + q3 * w1[192 + h] + q4 * w1[256 + h];
  float hi = b1[h + 1] + q0 * w1[h + 1]   + q1 * w1[64 + h + 1] + q2 * w1[128 + h + 1]
                       + q3 * w1[192 + h + 1] + q4 * w1[256 + h + 1];
  apk[(size_t)ps * 32 + h2] = pk2(fmaxf(lo, 0.f), fmaxf(hi, 0.f));
  if (h2 == 0) s2d[ps] = dst_off[d] + rd[e];
}

// ---------- fused per-iteration kernel ----------
// Phase A: T = feat_chunk @ M via MFMA (all 16 rows used). Phase B: per-node
// MFMA edge-GEMM (4 nodes/wave), msg stored packed f16 (o, o+16).
__global__ __launch_bounds__(256) void kTA(const float* __restrict__ feat,
                                           const uint4* __restrict__ Mpk2,
                                           const int* __restrict__ s2d,
                                           const unsigned int* __restrict__ apk,
                                           const int* __restrict__ src_off,
                                           unsigned int* __restrict__ msg16,
                                           int N){
  __shared__ unsigned int Tp[CHUNK * 1024];   // 64 KB, [node][o*32 + swz(word)]
  __shared__ float bias_l[CHUNK][33];
  int tid = threadIdx.x;
  int c0 = blockIdx.x * CHUNK;
  int c1 = min(c0 + CHUNK, N);
  int nvalid = c1 - c0;
  int w = tid >> 6, l = tid & 63;
  int m = l & 15, q = l >> 4;

  // ---- phase A ----
  {
    int nodeA = c0 + m;
    if (nodeA > c1 - 1) nodeA = c1 - 1;
    const float* fr = feat + (size_t)nodeA * 32 + q * 8;
    float4 fa = *(const float4*)fr;
    float4 fb = *(const float4*)(fr + 4);
    union { uint4 u; f16x8 h; } A;
    A.u.x = pk2(fa.x, fa.y); A.u.y = pk2(fa.z, fa.w);
    A.u.z = pk2(fb.x, fb.y); A.u.w = pk2(fb.z, fb.w);

#pragma unroll 4
    for (int jj2 = 0; jj2 < 16; jj2++){
      int job = w * 16 + jj2;
      int t = job >> 1, s = job & 1;
      int cE = 4 * t + s, cO = 4 * t + 2 + s;
      union { uint4 u; f16x8 h; } BE, BO;
      BE.u = Mpk2[cE * 64 + l];
      BO.u = Mpk2[cO * 64 + l];
      f32x4 z = {0.f, 0.f, 0.f, 0.f};
      f32x4 dE = __builtin_amdgcn_mfma_f32_16x16x32_f16(A.h, BE.h, z, 0, 0, 0);
      f32x4 dO = __builtin_amdgcn_mfma_f32_16x16x32_f16(A.h, BO.h, z, 0, 0, 0);
      int o = s * 16 + m;
      int sw = (((t >> 2) ^ (m & 7)) << 2) | (t & 3);
#pragma unroll
      for (int r = 0; r < 4; r++){
        int nn = q * 4 + r;
        if (nn < nvalid) Tp[nn * 1024 + o * 32 + sw] = pk2(dE[r], dO[r]);
      }
    }
    if (w == 3){   // bias row (job 64)
      union { uint4 u; f16x8 h; } BE, BO;
      BE.u = Mpk2[128 * 64 + l];
      BO.u = Mpk2[129 * 64 + l];
      f32x4 z = {0.f, 0.f, 0.f, 0.f};
      f32x4 dE = __builtin_amdgcn_mfma_f32_16x16x32_f16(A.h, BE.h, z, 0, 0, 0);
      f32x4 dO = __builtin_amdgcn_mfma_f32_16x16x32_f16(A.h, BO.h, z, 0, 0, 0);
#pragma unroll
      for (int r = 0; r < 4; r++){
        int nn = q * 4 + r;
        if (nn < nvalid){
          bias_l[nn][m]      = dE[r];
          bias_l[nn][16 + m] = dO[r];
        }
      }
    }
  }
  __syncthreads();

  // ---- phase B: per-node MFMA edge-GEMM (wave w handles nodes 4w..4w+3) ----
  for (int un = 0; un < 4; un++){
    int u = w * 4 + un;
    if (u >= nvalid) continue;
    int su = src_off[c0 + u], eu = src_off[c0 + u + 1];
    if (su >= eu) continue;
    const uint4* tb = (const uint4*)(Tp + u * 1024);
    union { uint4 u4; f16x8 h; } B00, B01, B10, B11;
    B00.u4 = tb[m * 8 + (q ^ (m & 7))];
    B10.u4 = tb[m * 8 + ((4 + q) ^ (m & 7))];
    B01.u4 = tb[(16 + m) * 8 + (q ^ (m & 7))];
    B11.u4 = tb[(16 + m) * 8 + ((4 + q) ^ (m & 7))];
    float b0 = bias_l[u][m], b1 = bias_l[u][16 + m];
    for (int jt = su; jt < eu; jt += 16){
      union { uint4 u4; f16x8 h; } A0, A1;
      const uint4* arow = (const uint4*)(apk + (size_t)(jt + m) * 32);
      A0.u4 = arow[q];
      A1.u4 = arow[4 + q];
      f32x4 z = {0.f, 0.f, 0.f, 0.f};
      f32x4 D0 = __builtin_amdgcn_mfma_f32_16x16x32_f16(A0.h, B00.h, z, 0, 0, 0);
      D0 = __builtin_amdgcn_mfma_f32_16x16x32_f16(A1.h, B10.h, D0, 0, 0, 0);
      f32x4 D1 = __builtin_amdgcn_mfma_f32_16x16x32_f16(A0.h, B01.h, z, 0, 0, 0);
      D1 = __builtin_amdgcn_mfma_f32_16x16x32_f16(A1.h, B11.h, D1, 0, 0, 0);
#pragma unroll
      for (int r = 0; r < 4; r++){
        int e = jt + q * 4 + r;
        if (e < eu){
          msg16[(size_t)s2d[e] * 16 + m] = pk2(D0[r] + b0, D1[r] + b1);
        }
      }
    }
  }
}

// aggregate packed msg (dst-ordered) + conv bias + relu + GRU (packed-f16 dot2)
__global__ __launch_bounds__(256) void kB(const unsigned int* __restrict__ msg16,
                                          const int* __restrict__ dst_off,
                                          const float* __restrict__ deg,
                                          const float* __restrict__ feat_in,
                                          float* __restrict__ feat_out,
                                          float* __restrict__ out2,
                                          const float* __restrict__ Wih,
                                          const float* __restrict__ Whh,
                                          const float* __restrict__ bih,
                                          const float* __restrict__ bhh,
                                          const float* __restrict__ cbias, int N){
  __shared__ unsigned int wihpk[96][17], whhpk[96][17];
  __shared__ float bi[96], bh[96], cb[32];
  __shared__ unsigned int mshpk[8][17], hshpk[8][17];
  int tid = threadIdx.x;
  for (int k = tid; k < 96 * 16; k += 256){
    int g = k >> 4, q2 = k & 15;
    wihpk[g][q2] = pk2(Wih[g * 32 + 2 * q2], Wih[g * 32 + 2 * q2 + 1]);
    whhpk[g][q2] = pk2(Whh[g * 32 + 2 * q2], Whh[g * 32 + 2 * q2 + 1]);
  }
  if (tid < 96){ bi[tid] = bih[tid]; bh[tid] = bhh[tid]; }
  if (tid < 32) cb[tid] = cbias[tid];
  __syncthreads();
  int s = tid >> 5, o = tid & 31;
  unsigned int sel = (o < 16) ? pk2(1.f, 0.f) : pk2(0.f, 1.f);
  int w16 = o & 15;
  for (int g8 = 0; g8 < KBN / 8; g8++){
    int v = blockIdx.x * KBN + g8 * 8 + s;
    if (v < N){
      int lo = dst_off[v], hi = dst_off[v + 1];
      float h = feat_in[(size_t)v * 32 + o];
      float a0 = 0.f, a1 = 0.f, a2 = 0.f, a3 = 0.f;
      int k = lo;
      for (; k + 3 < hi; k += 4){
        a0 = dot2(msg16[(size_t)(k + 0) * 16 + w16], sel, a0);
        a1 = dot2(msg16[(size_t)(k + 1) * 16 + w16], sel, a1);
        a2 = dot2(msg16[(size_t)(k + 2) * 16 + w16], sel, a2);
        a3 = dot2(msg16[(size_t)(k + 3) * 16 + w16], sel, a3);
      }
      for (; k < hi; k++) a0 = dot2(msg16[(size_t)k * 16 + w16], sel, a0);
      float acc = (a0 + a1) + (a2 + a3);
      float m = fmaxf(acc / deg[v] + cb[o], 0.f);
      float m1 = __shfl_down(m, 1);
      float h1 = __shfl_down(h, 1);
      if (!(o & 1)){
        mshpk[s][o >> 1] = pk2(m, m1);
        hshpk[s][o >> 1] = pk2(h, h1);
      }
      float gr = bi[o], gz = bi[32 + o], gn = bi[64 + o];
      float hr = bh[o], hz = bh[32 + o], hn = bh[64 + o];
#pragma unroll
      for (int q2 = 0; q2 < 16; q2++){
        unsigned int mq = mshpk[s][q2], hq = hshpk[s][q2];
        gr = dot2(mq, wihpk[o][q2], gr);
        gz = dot2(mq, wihpk[32 + o][q2], gz);
        gn = dot2(mq, wihpk[64 + o][q2], gn);
        hr = dot2(hq, whhpk[o][q2], hr);
        hz = dot2(hq, whhpk[32 + o][q2], hz);
        hn = dot2(hq, whhpk[64 + o][q2], hn);
      }
      float r = 1.f / (1.f + expf(-(gr + hr)));
      float z = 1.f / (1.f + expf(-(gz + hz)));
      float n = tanhf(gn + r * hn);
      float val = (1.f - z) * n + z * h;
      feat_out[(size_t)v * 32 + o] = val;
      if (out2) out2[(size_t)v * 32 + o] = val;
    }
  }
}

// ---------- fused Set2Set ----------
__global__ __launch_bounds__(256) void kS2S(const float* __restrict__ feat,
                                            const int* __restrict__ boff,
                                            const float* __restrict__ Wih,
                                            const float* __restrict__ Whh,
                                            const float* __restrict__ bih,
                                            const float* __restrict__ bhh,
                                            float* __restrict__ e_buf,
                                            float* __restrict__ out){
  int b = blockIdx.x;
  __shared__ float WihL[128][65];
  __shared__ float WhhL[128][33];
  __shared__ float qs[64], hst[32], cst[32], garr[128];
  __shared__ float wred[4];
  __shared__ float part[8][33];
  int tid = threadIdx.x;
  for (int k = tid; k < 128 * 64; k += 256) WihL[k >> 6][k & 63] = Wih[k];
  for (int k = tid; k < 128 * 32; k += 256) WhhL[k >> 5][k & 31] = Whh[k];
  if (tid < 64) qs[tid] = 0.f;
  if (tid < 32){ hst[tid] = 0.f; cst[tid] = 0.f; }
  __syncthreads();
  int lo = boff[b], hi = boff[b + 1];
  int sub = tid >> 5, o = tid & 31;
  for (int step = 0; step < 3; step++){
    if (tid < 128){
      float acc = bih[tid] + bhh[tid];
#pragma unroll 8
      for (int j = 0; j < 64; j++) acc += qs[j] * WihL[tid][j];
#pragma unroll 8
      for (int j = 0; j < 32; j++) acc += hst[j] * WhhL[tid][j];
      garr[tid] = acc;
    }
    __syncthreads();
    if (tid < 32){
      float iv = 1.f / (1.f + expf(-garr[tid]));
      float fv = 1.f / (1.f + expf(-garr[32 + tid]));
      float gv = tanhf(garr[64 + tid]);
      float ov = 1.f / (1.f + expf(-garr[96 + tid]));
      float c = fv * cst[tid] + iv * gv;
      cst[tid] = c;
      float hv = ov * tanhf(c);
      hst[tid] = hv;
      qs[tid] = hv;
    }
    __syncthreads();
    float mx = -1e30f;
    for (int i = lo + tid; i < hi; i += 256){
      const float* fr = feat + (size_t)i * 32;
      float acc = 0.f;
#pragma unroll
      for (int c4 = 0; c4 < 8; c4++){
        float4 f = *(const float4*)(fr + c4 * 4);
        acc += f.x * hst[c4 * 4] + f.y * hst[c4 * 4 + 1]
             + f.z * hst[c4 * 4 + 2] + f.w * hst[c4 * 4 + 3];
      }
      e_buf[i] = acc;
      mx = fmaxf(mx, acc);
    }
#pragma unroll
    for (int d2 = 32; d2; d2 >>= 1) mx = fmaxf(mx, __shfl_xor(mx, d2, 64));
    if ((tid & 63) == 0) wred[tid >> 6] = mx;
    __syncthreads();
    mx = fmaxf(fmaxf(wred[0], wred[1]), fmaxf(wred[2], wred[3]));
    __syncthreads();
    float sm = 0.f;
    for (int i = lo + tid; i < hi; i += 256){
      float w2 = expf(e_buf[i] - mx);
      e_buf[i] = w2;
      sm += w2;
    }
#pragma unroll
    for (int d2 = 32; d2; d2 >>= 1) sm += __shfl_xor(sm, d2, 64);
    if ((tid & 63) == 0) wred[tid >> 6] = sm;
    __syncthreads();
    float denom = fmaxf(wred[0] + wred[1] + wred[2] + wred[3], 1e-30f);
    float a0 = 0.f, a1 = 0.f, a2 = 0.f, a3 = 0.f;
    int i = lo + sub;
    for (; i + 24 < hi; i += 32){
      a0 += e_buf[i]      * feat[(size_t)i * 32 + o];
      a1 += e_buf[i + 8]  * feat[(size_t)(i + 8) * 32 + o];
      a2 += e_buf[i + 16] * feat[(size_t)(i + 16) * 32 + o];
      a3 += e_buf[i + 24] * feat[(size_t)(i + 24) * 32 + o];
    }
    for (; i < hi; i += 8) a0 += e_buf[i] * feat[(size_t)i * 32 + o];
    part[sub][o] = (a0 + a1) + (a2 + a3);
    __syncthreads();
    if (tid < 32){
      float r2 = 0.f;
#pragma unroll
      for (int s2 = 0; s2 < 8; s2++) r2 += part[s2][tid];
      qs[32 + tid] = r2 / denom;
    }
    __syncthreads();
  }
  if (tid < 64) out[b * 64 + tid] = qs[tid];
}

// ---------- host ----------

extern "C" void kernel_launch(void* const* d_in, const int* in_sizes, int n_in,
                              void* d_out, int out_size, void* d_ws, size_t ws_size,
                              hipStream_t stream){
  (void)n_in; (void)out_size; (void)ws_size;
  const float* x        = (const float*)d_in[0];
  const int*   ei       = (const int*)  d_in[1];
  const float* eattr    = (const float*)d_in[2];
  const int*   batch    = (const int*)  d_in[3];
  const float* lin0_w   = (const float*)d_in[4];
  const float* lin0_b   = (const float*)d_in[5];
  const float* mlp_w1   = (const float*)d_in[6];
  const float* mlp_b1   = (const float*)d_in[7];
  const float* mlp_w2   = (const float*)d_in[8];
  const float* mlp_b2   = (const float*)d_in[9];
  const float* conv_b   = (const float*)d_in[10];
  const float* gru_wih  = (const float*)d_in[11];
  const float* gru_whh  = (const float*)d_in[12];
  const float* gru_bih  = (const float*)d_in[13];
  const float* gru_bhh  = (const float*)d_in[14];
  const float* lstm_wih = (const float*)d_in[15];
  const float* lstm_whh = (const float*)d_in[16];
  const float* lstm_bih = (const float*)d_in[17];
  const float* lstm_bhh = (const float*)d_in[18];

  int N = in_sizes[0] / NFEAT;
  int E = in_sizes[1] / 2;
  int NT = (N + 255) / 256;

  char* ws = (char*)d_ws;
  size_t off = 0;
  auto alloc = [&](size_t bytes) -> char* {
    char* p = ws + off;
    off = align_up(off + bytes, 256);
    return p;
  };

  float* feat0  = (float*)alloc((size_t)N * D * 4);
  float* feat1  = (float*)alloc((size_t)N * D * 4);
  unsigned int* msg16 = (unsigned int*)alloc((size_t)E * 16 * 4);
  unsigned int* Mpk2 = (unsigned int*)alloc((size_t)130 * 64 * 4 * 4);
  unsigned int* apk = (unsigned int*)alloc((size_t)E * 32 * 4 + 4096);  // +pad: A-frag over-read
  float* e_buf  = (float*)alloc((size_t)N * 4);
  float* deg    = (float*)alloc((size_t)N * 4);
  int* cnt_src  = (int*)alloc((size_t)N * CPAD * 4);
  int* cnt_dst  = (int*)alloc((size_t)N * CPAD * 4);
  int* rs       = (int*)alloc((size_t)E * 4);
  int* rd       = (int*)alloc((size_t)E * 4);
  int* src_off  = (int*)alloc((size_t)(N + 1) * 4);
  int* dst_off  = (int*)alloc((size_t)(N + 1) * 4);
  int* boff     = (int*)alloc((size_t)(NB + 1) * 4);
  int* bsum     = (int*)alloc((size_t)2 * NT * 4);
  int* s2d      = (int*)alloc((size_t)E * 4 + 256);   // +pad

  (void)hipMemsetAsync(cnt_src, 0, (size_t)N * CPAD * 4 * 2, stream);

  kBuildMpk2<<<(130 * 64 * 4 + 255) / 256, 256, 0, stream>>>(mlp_w2, mlp_b2, Mpk2);
  kLin0<<<(N * 32 + 255) / 256, 256, 0, stream>>>(x, lin0_w, lin0_b, feat0, N);
  kCountRank<<<(E + 255) / 256, 256, 0, stream>>>(ei, cnt_src, cnt_dst, rs, rd, E);
  {
    dim3 gA(NT, 2);
    kScanA<<<gA, 256, 0, stream>>>(cnt_src, cnt_dst, src_off, dst_off, bsum, deg, N, NT);
    kScanB<<<1, 256, 0, stream>>>(bsum, batch, boff, src_off, dst_off, N, NT, NB, E);
    kScanC<<<gA, 256, 0, stream>>>(src_off, dst_off, bsum, N, NT);
  }
  kEdgeMLPpk<<<((size_t)E * 32 + 255) / 256, 256, 0, stream>>>(eattr, mlp_w1, mlp_b1,
                                                               ei, src_off, dst_off,
                                                               rs, rd, apk, s2d, E);

  int blocksTA = (N + CHUNK - 1) / CHUNK;
  float* fcur = feat0;
  float* fnext = feat1;
  for (int t = 0; t < 3; t++){
    kTA<<<blocksTA, 256, 0, stream>>>(fcur, (const uint4*)Mpk2, s2d, apk,
                                      src_off, msg16, N);
    float* out2 = (t == 2) ? ((float*)d_out + NB * 64) : nullptr;
    kB<<<(N + KBN - 1) / KBN, 256, 0, stream>>>(msg16, dst_off, deg, fcur, fnext, out2,
                                                gru_wih, gru_whh, gru_bih, gru_bhh,
                                                conv_b, N);
    float* tmp = fcur; fcur = fnext; fnext = tmp;
  }

  kS2S<<<NB, 256, 0, stream>>>(fcur, boff, lstm_wih, lstm_whh, lstm_bih, lstm_bhh,
                               e_buf, (float*)d_out);
}

// Round 19
// 298.306 us; speedup vs baseline: 1.0964x; 1.0964x over previous
//
#include <hip/hip_runtime.h>
#include <hip/hip_fp16.h>

#define NFEAT 16
#define D 32
#define NB 64        // num graphs
#define TCOLS 2080   // 65*32
#define CHUNK 8      // nodes per fused block (measured best: 34KB LDS, 4 blocks/CU)
#define CPAD 16      // counter padding: one counter per 64B line
#define KBN 16       // nodes per kB block

static inline size_t align_up(size_t x, size_t a){ return (x + a - 1) & ~(a - 1); }

typedef _Float16 f16x2 __attribute__((ext_vector_type(2)));
typedef _Float16 f16x8 __attribute__((ext_vector_type(8)));
typedef float f32x4 __attribute__((ext_vector_type(4)));

__device__ inline unsigned int pk2(float a, float b){
  __half2 h = __floats2half2_rn(a, b);
  union { __half2 h; unsigned int u; } cv; cv.h = h; return cv.u;
}

__device__ inline float dot2(unsigned int a, unsigned int b, float c){
  union { unsigned int u; f16x2 h; } ua, ub; ua.u = a; ub.u = b;
#if __has_builtin(__builtin_amdgcn_fdot2)
  return __builtin_amdgcn_fdot2(ua.h, ub.h, c, false);
#else
  return c + (float)ua.h[0] * (float)ub.h[0] + (float)ua.h[1] * (float)ub.h[1];
#endif
}

// ---------- setup kernels ----------

// B-fragment layout for v_mfma_f32_16x16x32_f16 (tile c: cols c*16..+15, col=h*32+o)
__global__ __launch_bounds__(256) void kBuildMpk2(const float* __restrict__ w2,
                                                  const float* __restrict__ b2,
                                                  unsigned int* __restrict__ Mpk2){
  int idx = blockIdx.x * 256 + threadIdx.x;
  if (idx >= 130 * 64 * 4) return;
  int j2 = idx & 3;
  int l  = (idx >> 2) & 63;
  int c  = idx >> 8;
  int col = c * 16 + (l & 15);
  int h = col >> 5, o = col & 31;
  int ke = (l >> 4) * 8 + 2 * j2;
  float f0, f1;
  if (h < 64){
    f0 = w2[h * 1024 + ke * 32 + o];
    f1 = w2[h * 1024 + (ke + 1) * 32 + o];
  } else {
    f0 = b2[ke * 32 + o];
    f1 = b2[(ke + 1) * 32 + o];
  }
  Mpk2[idx] = pk2(f0, f1);
}

__global__ __launch_bounds__(256) void kLin0(const float* __restrict__ x,
                                             const float* __restrict__ w,
                                             const float* __restrict__ b,
                                             float* __restrict__ feat, int N){
  int idx = blockIdx.x * 256 + threadIdx.x;
  int u = idx >> 5, o = idx & 31;
  if (u >= N) return;
  float acc = b[o];
#pragma unroll
  for (int i = 0; i < NFEAT; i++) acc += x[(size_t)u * NFEAT + i] * w[i * 32 + o];
  feat[idx] = fmaxf(acc, 0.f);
}

// counts (padded) + ranks in one pass
__global__ __launch_bounds__(256) void kCountRank(const int* __restrict__ ei,
                                                  int* __restrict__ cnt_src,
                                                  int* __restrict__ cnt_dst,
                                                  int* __restrict__ rs,
                                                  int* __restrict__ rd, int E){
  int e = blockIdx.x * 256 + threadIdx.x;
  if (e >= E) return;
  int s = ei[e], d = ei[E + e];
  rs[e] = atomicAdd(&cnt_src[(size_t)s * CPAD], 1);
  rd[e] = atomicAdd(&cnt_dst[(size_t)d * CPAD], 1);
}

// hierarchical scan, stage A: per-256-tile block scan; grid (NT, 2)
__global__ __launch_bounds__(256) void kScanA(const int* __restrict__ cnt_src,
                                              const int* __restrict__ cnt_dst,
                                              int* __restrict__ src_off,
                                              int* __restrict__ dst_off,
                                              int* __restrict__ bsum,
                                              float* __restrict__ deg,
                                              int N, int NT){
  int y = blockIdx.y;
  const int* cnt = y ? cnt_dst : cnt_src;
  int* off = y ? dst_off : src_off;
  int t = threadIdx.x;
  int i = blockIdx.x * 256 + t;
  int c = (i < N) ? cnt[(size_t)i * CPAD] : 0;
  if (y && i < N) deg[i] = (float)max(c, 1);
  __shared__ int sh[256];
  sh[t] = c; __syncthreads();
  for (int d = 1; d < 256; d <<= 1){
    int v = (t >= d) ? sh[t - d] : 0;
    __syncthreads();
    sh[t] += v;
    __syncthreads();
  }
  if (i < N) off[i] = sh[t] - c;           // within-tile exclusive
  if (t == 255) bsum[y * NT + blockIdx.x] = sh[255];
}

// stage B: scan tile sums (NT<=256) + batch offsets via bsearch
__global__ __launch_bounds__(256) void kScanB(int* __restrict__ bsum,
                                              const int* __restrict__ batch,
                                              int* __restrict__ boff,
                                              int* __restrict__ src_off,
                                              int* __restrict__ dst_off,
                                              int N, int NT, int B, int E){
  int t = threadIdx.x;
  __shared__ int sh[256];
  for (int y = 0; y < 2; y++){
    int v = (t < NT) ? bsum[y * NT + t] : 0;
    sh[t] = v; __syncthreads();
    for (int d = 1; d < 256; d <<= 1){
      int u = (t >= d) ? sh[t - d] : 0;
      __syncthreads();
      sh[t] += u;
      __syncthreads();
    }
    if (t < NT) bsum[y * NT + t] = sh[t] - v;   // exclusive tile offset
    __syncthreads();
  }
  if (t <= B){
    int lo = 0, hi = N;
    while (lo < hi){ int mid = (lo + hi) >> 1; if (batch[mid] < t) lo = mid + 1; else hi = mid; }
    boff[t] = lo;
  }
  if (t == 0){ src_off[N] = E; dst_off[N] = E; }
}

// stage C: add tile offsets; grid (NT, 2)
__global__ __launch_bounds__(256) void kScanC(int* __restrict__ src_off,
                                              int* __restrict__ dst_off,
                                              const int* __restrict__ bsum,
                                              int N, int NT){
  int y = blockIdx.y;
  int i = blockIdx.x * 256 + threadIdx.x;
  if (i < N) (y ? dst_off : src_off)[i] += bsum[y * NT + blockIdx.x];
}

// fused placement + edge MLP: edge e (original order), 32 lanes per edge.
// writes apk row at src-CSR position ps (128B-contiguous scatter) and s2d.
__global__ __launch_bounds__(256) void kEdgeMLPpk(const float* __restrict__ ea,
                                                  const float* __restrict__ w1,
                                                  const float* __restrict__ b1,
                                                  const int* __restrict__ ei,
                                                  const int* __restrict__ src_off,
                                                  const int* __restrict__ dst_off,
                                                  const int* __restrict__ rs,
                                                  const int* __restrict__ rd,
                                                  unsigned int* __restrict__ apk,
                                                  int* __restrict__ s2d, int E){
  int idx = blockIdx.x * 256 + threadIdx.x;
  int e = idx >> 5, h2 = idx & 31;
  if (e >= E) return;
  int s = ei[e], d = ei[E + e];
  int ps = src_off[s] + rs[e];
  const float* eap = ea + (size_t)e * 5;
  float q0 = eap[0], q1 = eap[1], q2 = eap[2], q3 = eap[3], q4 = eap[4];
  int h = 2 * h2;
  float lo = b1[h]     + q0 * w1[h]       + q1 * w1[64 + h]     + q2 * w1[128 + h]
                       + q3 * w1[192 + h] + q4 * w1[256 + h];
  float hi = b1[h + 1] + q0 * w1[h + 1]   + q1 * w1[64 + h + 1] + q2 * w1[128 + h + 1]
                       + q3 * w1[192 + h + 1] + q4 * w1[256 + h + 1];
  apk[(size_t)ps * 32 + h2] = pk2(fmaxf(lo, 0.f), fmaxf(hi, 0.f));
  if (h2 == 0) s2d[ps] = dst_off[d] + rd[e];
}

// ---------- fused per-iteration kernel ----------
// Phase A: T = feat_chunk @ M via MFMA; contiguous branch-free job loop,
// unroll-4 for L2-latency pipelining. Phase B: per-node MFMA edge-GEMM,
// msg stored as packed f16 pairs (o, o+16).
__global__ __launch_bounds__(256, 4) void kTA(const float* __restrict__ feat,
                                              const uint4* __restrict__ Mpk2,
                                              const int* __restrict__ s2d,
                                              const unsigned int* __restrict__ apk,
                                              const int* __restrict__ src_off,
                                              unsigned int* __restrict__ msg16,
                                              int N){
  __shared__ unsigned int Tp[CHUNK * 1024];   // 32 KB, [node][o*32 + swz(word)]
  __shared__ float bias_l[CHUNK][33];
  int tid = threadIdx.x;
  int c0 = blockIdx.x * CHUNK;
  int c1 = min(c0 + CHUNK, N);
  int nvalid = c1 - c0;
  int w = tid >> 6, l = tid & 63;
  int m = l & 15, q = l >> 4;

  // ---- phase A ----
  {
    int nodeA = c0 + m;
    if (nodeA > c1 - 1) nodeA = c1 - 1;
    const float* fr = feat + (size_t)nodeA * 32 + q * 8;
    float4 fa = *(const float4*)fr;
    float4 fb = *(const float4*)(fr + 4);
    union { uint4 u; f16x8 h; } A;
    A.u.x = pk2(fa.x, fa.y); A.u.y = pk2(fa.z, fa.w);
    A.u.z = pk2(fb.x, fb.y); A.u.w = pk2(fb.z, fb.w);

#pragma unroll 4
    for (int jj2 = 0; jj2 < 16; jj2++){
      int job = w * 16 + jj2;
      int t = job >> 1, s = job & 1;
      int cE = 4 * t + s, cO = 4 * t + 2 + s;
      union { uint4 u; f16x8 h; } BE, BO;
      BE.u = Mpk2[cE * 64 + l];
      BO.u = Mpk2[cO * 64 + l];
      f32x4 z = {0.f, 0.f, 0.f, 0.f};
      f32x4 dE = __builtin_amdgcn_mfma_f32_16x16x32_f16(A.h, BE.h, z, 0, 0, 0);
      f32x4 dO = __builtin_amdgcn_mfma_f32_16x16x32_f16(A.h, BO.h, z, 0, 0, 0);
      int o = s * 16 + m;
      int sw = (((t >> 2) ^ (m & 7)) << 2) | (t & 3);
#pragma unroll
      for (int r = 0; r < 4; r++){
        int nn = q * 4 + r;
        if (nn < nvalid) Tp[nn * 1024 + o * 32 + sw] = pk2(dE[r], dO[r]);
      }
    }
    if (w == 3){   // bias row (job 64)
      union { uint4 u; f16x8 h; } BE, BO;
      BE.u = Mpk2[128 * 64 + l];
      BO.u = Mpk2[129 * 64 + l];
      f32x4 z = {0.f, 0.f, 0.f, 0.f};
      f32x4 dE = __builtin_amdgcn_mfma_f32_16x16x32_f16(A.h, BE.h, z, 0, 0, 0);
      f32x4 dO = __builtin_amdgcn_mfma_f32_16x16x32_f16(A.h, BO.h, z, 0, 0, 0);
#pragma unroll
      for (int r = 0; r < 4; r++){
        int nn = q * 4 + r;
        if (nn < nvalid){
          bias_l[nn][m]      = dE[r];
          bias_l[nn][16 + m] = dO[r];
        }
      }
    }
  }
  __syncthreads();

  // ---- phase B: per-node MFMA edge-GEMM (wave w handles nodes 2w, 2w+1) ----
  for (int un = 0; un < 2; un++){
    int u = w * 2 + un;
    if (u >= nvalid) continue;
    int su = src_off[c0 + u], eu = src_off[c0 + u + 1];
    if (su >= eu) continue;
    const uint4* tb = (const uint4*)(Tp + u * 1024);
    union { uint4 u4; f16x8 h; } B00, B01, B10, B11;
    B00.u4 = tb[m * 8 + (q ^ (m & 7))];
    B10.u4 = tb[m * 8 + ((4 + q) ^ (m & 7))];
    B01.u4 = tb[(16 + m) * 8 + (q ^ (m & 7))];
    B11.u4 = tb[(16 + m) * 8 + ((4 + q) ^ (m & 7))];
    float b0 = bias_l[u][m], b1 = bias_l[u][16 + m];
    for (int jt = su; jt < eu; jt += 16){
      union { uint4 u4; f16x8 h; } A0, A1;
      const uint4* arow = (const uint4*)(apk + (size_t)(jt + m) * 32);
      A0.u4 = arow[q];
      A1.u4 = arow[4 + q];
      f32x4 z = {0.f, 0.f, 0.f, 0.f};
      f32x4 D0 = __builtin_amdgcn_mfma_f32_16x16x32_f16(A0.h, B00.h, z, 0, 0, 0);
      D0 = __builtin_amdgcn_mfma_f32_16x16x32_f16(A1.h, B10.h, D0, 0, 0, 0);
      f32x4 D1 = __builtin_amdgcn_mfma_f32_16x16x32_f16(A0.h, B01.h, z, 0, 0, 0);
      D1 = __builtin_amdgcn_mfma_f32_16x16x32_f16(A1.h, B11.h, D1, 0, 0, 0);
#pragma unroll
      for (int r = 0; r < 4; r++){
        int e = jt + q * 4 + r;
        if (e < eu){
          msg16[(size_t)s2d[e] * 16 + m] = pk2(D0[r] + b0, D1[r] + b1);
        }
      }
    }
  }
}

// aggregate packed msg (dst-ordered) + conv bias + relu + GRU (packed-f16 dot2)
__global__ __launch_bounds__(256) void kB(const unsigned int* __restrict__ msg16,
                                          const int* __restrict__ dst_off,
                                          const float* __restrict__ deg,
                                          const float* __restrict__ feat_in,
                                          float* __restrict__ feat_out,
                                          float* __restrict__ out2,
                                          const float* __restrict__ Wih,
                                          const float* __restrict__ Whh,
                                          const float* __restrict__ bih,
                                          const float* __restrict__ bhh,
                                          const float* __restrict__ cbias, int N){
  __shared__ unsigned int wihpk[96][17], whhpk[96][17];
  __shared__ float bi[96], bh[96], cb[32];
  __shared__ unsigned int mshpk[8][17], hshpk[8][17];
  int tid = threadIdx.x;
  for (int k = tid; k < 96 * 16; k += 256){
    int g = k >> 4, q2 = k & 15;
    wihpk[g][q2] = pk2(Wih[g * 32 + 2 * q2], Wih[g * 32 + 2 * q2 + 1]);
    whhpk[g][q2] = pk2(Whh[g * 32 + 2 * q2], Whh[g * 32 + 2 * q2 + 1]);
  }
  if (tid < 96){ bi[tid] = bih[tid]; bh[tid] = bhh[tid]; }
  if (tid < 32) cb[tid] = cbias[tid];
  __syncthreads();
  int s = tid >> 5, o = tid & 31;
  unsigned int sel = (o < 16) ? pk2(1.f, 0.f) : pk2(0.f, 1.f);
  int w16 = o & 15;
  for (int g8 = 0; g8 < KBN / 8; g8++){
    int v = blockIdx.x * KBN + g8 * 8 + s;
    if (v < N){
      int lo = dst_off[v], hi = dst_off[v + 1];
      float h = feat_in[(size_t)v * 32 + o];
      float a0 = 0.f, a1 = 0.f, a2 = 0.f, a3 = 0.f;
      int k = lo;
      for (; k + 3 < hi; k += 4){
        a0 = dot2(msg16[(size_t)(k + 0) * 16 + w16], sel, a0);
        a1 = dot2(msg16[(size_t)(k + 1) * 16 + w16], sel, a1);
        a2 = dot2(msg16[(size_t)(k + 2) * 16 + w16], sel, a2);
        a3 = dot2(msg16[(size_t)(k + 3) * 16 + w16], sel, a3);
      }
      for (; k < hi; k++) a0 = dot2(msg16[(size_t)k * 16 + w16], sel, a0);
      float acc = (a0 + a1) + (a2 + a3);
      float m = fmaxf(acc / deg[v] + cb[o], 0.f);
      float m1 = __shfl_down(m, 1);
      float h1 = __shfl_down(h, 1);
      if (!(o & 1)){
        mshpk[s][o >> 1] = pk2(m, m1);
        hshpk[s][o >> 1] = pk2(h, h1);
      }
      float gr = bi[o], gz = bi[32 + o], gn = bi[64 + o];
      float hr = bh[o], hz = bh[32 + o], hn = bh[64 + o];
#pragma unroll
      for (int q2 = 0; q2 < 16; q2++){
        unsigned int mq = mshpk[s][q2], hq = hshpk[s][q2];
        gr = dot2(mq, wihpk[o][q2], gr);
        gz = dot2(mq, wihpk[32 + o][q2], gz);
        gn = dot2(mq, wihpk[64 + o][q2], gn);
        hr = dot2(hq, whhpk[o][q2], hr);
        hz = dot2(hq, whhpk[32 + o][q2], hz);
        hn = dot2(hq, whhpk[64 + o][q2], hn);
      }
      float r = 1.f / (1.f + expf(-(gr + hr)));
      float z = 1.f / (1.f + expf(-(gz + hz)));
      float n = tanhf(gn + r * hn);
      float val = (1.f - z) * n + z * h;
      feat_out[(size_t)v * 32 + o] = val;
      if (out2) out2[(size_t)v * 32 + o] = val;
    }
  }
}

// ---------- fused Set2Set ----------
__global__ __launch_bounds__(256) void kS2S(const float* __restrict__ feat,
                                            const int* __restrict__ boff,
                                            const float* __restrict__ Wih,
                                            const float* __restrict__ Whh,
                                            const float* __restrict__ bih,
                                            const float* __restrict__ bhh,
                                            float* __restrict__ e_buf,
                                            float* __restrict__ out){
  int b = blockIdx.x;
  __shared__ float WihL[128][65];
  __shared__ float WhhL[128][33];
  __shared__ float qs[64], hst[32], cst[32], garr[128];
  __shared__ float wred[4];
  __shared__ float part[8][33];
  int tid = threadIdx.x;
  for (int k = tid; k < 128 * 64; k += 256) WihL[k >> 6][k & 63] = Wih[k];
  for (int k = tid; k < 128 * 32; k += 256) WhhL[k >> 5][k & 31] = Whh[k];
  if (tid < 64) qs[tid] = 0.f;
  if (tid < 32){ hst[tid] = 0.f; cst[tid] = 0.f; }
  __syncthreads();
  int lo = boff[b], hi = boff[b + 1];
  int sub = tid >> 5, o = tid & 31;
  for (int step = 0; step < 3; step++){
    if (tid < 128){
      float acc = bih[tid] + bhh[tid];
#pragma unroll 8
      for (int j = 0; j < 64; j++) acc += qs[j] * WihL[tid][j];
#pragma unroll 8
      for (int j = 0; j < 32; j++) acc += hst[j] * WhhL[tid][j];
      garr[tid] = acc;
    }
    __syncthreads();
    if (tid < 32){
      float iv = 1.f / (1.f + expf(-garr[tid]));
      float fv = 1.f / (1.f + expf(-garr[32 + tid]));
      float gv = tanhf(garr[64 + tid]);
      float ov = 1.f / (1.f + expf(-garr[96 + tid]));
      float c = fv * cst[tid] + iv * gv;
      cst[tid] = c;
      float hv = ov * tanhf(c);
      hst[tid] = hv;
      qs[tid] = hv;
    }
    __syncthreads();
    float mx = -1e30f;
    for (int i = lo + tid; i < hi; i += 256){
      const float* fr = feat + (size_t)i * 32;
      float acc = 0.f;
#pragma unroll
      for (int c4 = 0; c4 < 8; c4++){
        float4 f = *(const float4*)(fr + c4 * 4);
        acc += f.x * hst[c4 * 4] + f.y * hst[c4 * 4 + 1]
             + f.z * hst[c4 * 4 + 2] + f.w * hst[c4 * 4 + 3];
      }
      e_buf[i] = acc;
      mx = fmaxf(mx, acc);
    }
#pragma unroll
    for (int d2 = 32; d2; d2 >>= 1) mx = fmaxf(mx, __shfl_xor(mx, d2, 64));
    if ((tid & 63) == 0) wred[tid >> 6] = mx;
    __syncthreads();
    mx = fmaxf(fmaxf(wred[0], wred[1]), fmaxf(wred[2], wred[3]));
    __syncthreads();
    float sm = 0.f;
    for (int i = lo + tid; i < hi; i += 256){
      float w2 = expf(e_buf[i] - mx);
      e_buf[i] = w2;
      sm += w2;
    }
#pragma unroll
    for (int d2 = 32; d2; d2 >>= 1) sm += __shfl_xor(sm, d2, 64);
    if ((tid & 63) == 0) wred[tid >> 6] = sm;
    __syncthreads();
    float denom = fmaxf(wred[0] + wred[1] + wred[2] + wred[3], 1e-30f);
    float a0 = 0.f, a1 = 0.f, a2 = 0.f, a3 = 0.f;
    int i = lo + sub;
    for (; i + 24 < hi; i += 32){
      a0 += e_buf[i]      * feat[(size_t)i * 32 + o];
      a1 += e_buf[i + 8]  * feat[(size_t)(i + 8) * 32 + o];
      a2 += e_buf[i + 16] * feat[(size_t)(i + 16) * 32 + o];
      a3 += e_buf[i + 24] * feat[(size_t)(i + 24) * 32 + o];
    }
    for (; i < hi; i += 8) a0 += e_buf[i] * feat[(size_t)i * 32 + o];
    part[sub][o] = (a0 + a1) + (a2 + a3);
    __syncthreads();
    if (tid < 32){
      float r2 = 0.f;
#pragma unroll
      for (int s2 = 0; s2 < 8; s2++) r2 += part[s2][tid];
      qs[32 + tid] = r2 / denom;
    }
    __syncthreads();
  }
  if (tid < 64) out[b * 64 + tid] = qs[tid];
}

// ---------- host ----------

extern "C" void kernel_launch(void* const* d_in, const int* in_sizes, int n_in,
                              void* d_out, int out_size, void* d_ws, size_t ws_size,
                              hipStream_t stream){
  (void)n_in; (void)out_size; (void)ws_size;
  const float* x        = (const float*)d_in[0];
  const int*   ei       = (const int*)  d_in[1];
  const float* eattr    = (const float*)d_in[2];
  const int*   batch    = (const int*)  d_in[3];
  const float* lin0_w   = (const float*)d_in[4];
  const float* lin0_b   = (const float*)d_in[5];
  const float* mlp_w1   = (const float*)d_in[6];
  const float* mlp_b1   = (const float*)d_in[7];
  const float* mlp_w2   = (const float*)d_in[8];
  const float* mlp_b2   = (const float*)d_in[9];
  const float* conv_b   = (const float*)d_in[10];
  const float* gru_wih  = (const float*)d_in[11];
  const float* gru_whh  = (const float*)d_in[12];
  const float* gru_bih  = (const float*)d_in[13];
  const float* gru_bhh  = (const float*)d_in[14];
  const float* lstm_wih = (const float*)d_in[15];
  const float* lstm_whh = (const float*)d_in[16];
  const float* lstm_bih = (const float*)d_in[17];
  const float* lstm_bhh = (const float*)d_in[18];

  int N = in_sizes[0] / NFEAT;
  int E = in_sizes[1] / 2;
  int NT = (N + 255) / 256;

  char* ws = (char*)d_ws;
  size_t off = 0;
  auto alloc = [&](size_t bytes) -> char* {
    char* p = ws + off;
    off = align_up(off + bytes, 256);
    return p;
  };

  float* feat0  = (float*)alloc((size_t)N * D * 4);
  float* feat1  = (float*)alloc((size_t)N * D * 4);
  unsigned int* msg16 = (unsigned int*)alloc((size_t)E * 16 * 4);
  unsigned int* Mpk2 = (unsigned int*)alloc((size_t)130 * 64 * 4 * 4);
  unsigned int* apk = (unsigned int*)alloc((size_t)E * 32 * 4 + 4096);  // +pad: A-frag over-read
  float* e_buf  = (float*)alloc((size_t)N * 4);
  float* deg    = (float*)alloc((size_t)N * 4);
  int* cnt_src  = (int*)alloc((size_t)N * CPAD * 4);
  int* cnt_dst  = (int*)alloc((size_t)N * CPAD * 4);
  int* rs       = (int*)alloc((size_t)E * 4);
  int* rd       = (int*)alloc((size_t)E * 4);
  int* src_off  = (int*)alloc((size_t)(N + 1) * 4);
  int* dst_off  = (int*)alloc((size_t)(N + 1) * 4);
  int* boff     = (int*)alloc((size_t)(NB + 1) * 4);
  int* bsum     = (int*)alloc((size_t)2 * NT * 4);
  int* s2d      = (int*)alloc((size_t)E * 4 + 256);   // +pad

  (void)hipMemsetAsync(cnt_src, 0, (size_t)N * CPAD * 4 * 2, stream);

  kBuildMpk2<<<(130 * 64 * 4 + 255) / 256, 256, 0, stream>>>(mlp_w2, mlp_b2, Mpk2);
  kLin0<<<(N * 32 + 255) / 256, 256, 0, stream>>>(x, lin0_w, lin0_b, feat0, N);
  kCountRank<<<(E + 255) / 256, 256, 0, stream>>>(ei, cnt_src, cnt_dst, rs, rd, E);
  {
    dim3 gA(NT, 2);
    kScanA<<<gA, 256, 0, stream>>>(cnt_src, cnt_dst, src_off, dst_off, bsum, deg, N, NT);
    kScanB<<<1, 256, 0, stream>>>(bsum, batch, boff, src_off, dst_off, N, NT, NB, E);
    kScanC<<<gA, 256, 0, stream>>>(src_off, dst_off, bsum, N, NT);
  }
  kEdgeMLPpk<<<((size_t)E * 32 + 255) / 256, 256, 0, stream>>>(eattr, mlp_w1, mlp_b1,
                                                               ei, src_off, dst_off,
                                                               rs, rd, apk, s2d, E);

  int blocksTA = (N + CHUNK - 1) / CHUNK;
  float* fcur = feat0;
  float* fnext = feat1;
  for (int t = 0; t < 3; t++){
    kTA<<<blocksTA, 256, 0, stream>>>(fcur, (const uint4*)Mpk2, s2d, apk,
                                      src_off, msg16, N);
    float* out2 = (t == 2) ? ((float*)d_out + NB * 64) : nullptr;
    kB<<<(N + KBN - 1) / KBN, 256, 0, stream>>>(msg16, dst_off, deg, fcur, fnext, out2,
                                                gru_wih, gru_whh, gru_bih, gru_bhh,
                                                conv_b, N);
    float* tmp = fcur; fcur = fnext; fnext = tmp;
  }

  kS2S<<<NB, 256, 0, stream>>>(fcur, boff, lstm_wih, lstm_whh, lstm_bih, lstm_bhh,
                               e_buf, (float*)d_out);
}

// Round 20
// 274.464 us; speedup vs baseline: 1.1917x; 1.0869x over previous
//
#include <hip/hip_runtime.h>
#include <hip/hip_fp16.h>

#define NFEAT 16
#define D 32
#define NB 64        // num graphs
#define TCOLS 2080   // 65*32
#define CHUNK 16     // nodes per fused block (512-thread: 8 waves, all MFMA rows used)
#define CPAD 16      // counter padding: one counter per 64B line
#define KBN 16       // nodes per kB block

static inline size_t align_up(size_t x, size_t a){ return (x + a - 1) & ~(a - 1); }

typedef _Float16 f16x2 __attribute__((ext_vector_type(2)));
typedef _Float16 f16x8 __attribute__((ext_vector_type(8)));
typedef float f32x4 __attribute__((ext_vector_type(4)));

__device__ inline unsigned int pk2(float a, float b){
  __half2 h = __floats2half2_rn(a, b);
  union { __half2 h; unsigned int u; } cv; cv.h = h; return cv.u;
}

__device__ inline float dot2(unsigned int a, unsigned int b, float c){
  union { unsigned int u; f16x2 h; } ua, ub; ua.u = a; ub.u = b;
#if __has_builtin(__builtin_amdgcn_fdot2)
  return __builtin_amdgcn_fdot2(ua.h, ub.h, c, false);
#else
  return c + (float)ua.h[0] * (float)ub.h[0] + (float)ua.h[1] * (float)ub.h[1];
#endif
}

// ---------- setup kernels ----------

// B-fragment layout for v_mfma_f32_16x16x32_f16 (tile c: cols c*16..+15, col=h*32+o)
__global__ __launch_bounds__(256) void kBuildMpk2(const float* __restrict__ w2,
                                                  const float* __restrict__ b2,
                                                  unsigned int* __restrict__ Mpk2){
  int idx = blockIdx.x * 256 + threadIdx.x;
  if (idx >= 130 * 64 * 4) return;
  int j2 = idx & 3;
  int l  = (idx >> 2) & 63;
  int c  = idx >> 8;
  int col = c * 16 + (l & 15);
  int h = col >> 5, o = col & 31;
  int ke = (l >> 4) * 8 + 2 * j2;
  float f0, f1;
  if (h < 64){
    f0 = w2[h * 1024 + ke * 32 + o];
    f1 = w2[h * 1024 + (ke + 1) * 32 + o];
  } else {
    f0 = b2[ke * 32 + o];
    f1 = b2[(ke + 1) * 32 + o];
  }
  Mpk2[idx] = pk2(f0, f1);
}

__global__ __launch_bounds__(256) void kLin0(const float* __restrict__ x,
                                             const float* __restrict__ w,
                                             const float* __restrict__ b,
                                             float* __restrict__ feat, int N){
  int idx = blockIdx.x * 256 + threadIdx.x;
  int u = idx >> 5, o = idx & 31;
  if (u >= N) return;
  float acc = b[o];
#pragma unroll
  for (int i = 0; i < NFEAT; i++) acc += x[(size_t)u * NFEAT + i] * w[i * 32 + o];
  feat[idx] = fmaxf(acc, 0.f);
}

// counts (padded) + ranks in one pass
__global__ __launch_bounds__(256) void kCountRank(const int* __restrict__ ei,
                                                  int* __restrict__ cnt_src,
                                                  int* __restrict__ cnt_dst,
                                                  int* __restrict__ rs,
                                                  int* __restrict__ rd, int E){
  int e = blockIdx.x * 256 + threadIdx.x;
  if (e >= E) return;
  int s = ei[e], d = ei[E + e];
  rs[e] = atomicAdd(&cnt_src[(size_t)s * CPAD], 1);
  rd[e] = atomicAdd(&cnt_dst[(size_t)d * CPAD], 1);
}

// hierarchical scan, stage A: per-256-tile block scan; grid (NT, 2)
__global__ __launch_bounds__(256) void kScanA(const int* __restrict__ cnt_src,
                                              const int* __restrict__ cnt_dst,
                                              int* __restrict__ src_off,
                                              int* __restrict__ dst_off,
                                              int* __restrict__ bsum,
                                              float* __restrict__ deg,
                                              int N, int NT){
  int y = blockIdx.y;
  const int* cnt = y ? cnt_dst : cnt_src;
  int* off = y ? dst_off : src_off;
  int t = threadIdx.x;
  int i = blockIdx.x * 256 + t;
  int c = (i < N) ? cnt[(size_t)i * CPAD] : 0;
  if (y && i < N) deg[i] = (float)max(c, 1);
  __shared__ int sh[256];
  sh[t] = c; __syncthreads();
  for (int d = 1; d < 256; d <<= 1){
    int v = (t >= d) ? sh[t - d] : 0;
    __syncthreads();
    sh[t] += v;
    __syncthreads();
  }
  if (i < N) off[i] = sh[t] - c;           // within-tile exclusive
  if (t == 255) bsum[y * NT + blockIdx.x] = sh[255];
}

// stage B: scan tile sums (NT<=256) + batch offsets via bsearch
__global__ __launch_bounds__(256) void kScanB(int* __restrict__ bsum,
                                              const int* __restrict__ batch,
                                              int* __restrict__ boff,
                                              int* __restrict__ src_off,
                                              int* __restrict__ dst_off,
                                              int N, int NT, int B, int E){
  int t = threadIdx.x;
  __shared__ int sh[256];
  for (int y = 0; y < 2; y++){
    int v = (t < NT) ? bsum[y * NT + t] : 0;
    sh[t] = v; __syncthreads();
    for (int d = 1; d < 256; d <<= 1){
      int u = (t >= d) ? sh[t - d] : 0;
      __syncthreads();
      sh[t] += u;
      __syncthreads();
    }
    if (t < NT) bsum[y * NT + t] = sh[t] - v;   // exclusive tile offset
    __syncthreads();
  }
  if (t <= B){
    int lo = 0, hi = N;
    while (lo < hi){ int mid = (lo + hi) >> 1; if (batch[mid] < t) lo = mid + 1; else hi = mid; }
    boff[t] = lo;
  }
  if (t == 0){ src_off[N] = E; dst_off[N] = E; }
}

// stage C: add tile offsets; grid (NT, 2)
__global__ __launch_bounds__(256) void kScanC(int* __restrict__ src_off,
                                              int* __restrict__ dst_off,
                                              const int* __restrict__ bsum,
                                              int N, int NT){
  int y = blockIdx.y;
  int i = blockIdx.x * 256 + threadIdx.x;
  if (i < N) (y ? dst_off : src_off)[i] += bsum[y * NT + blockIdx.x];
}

// fused placement + edge MLP: edge e (original order), 32 lanes per edge.
__global__ __launch_bounds__(256) void kEdgeMLPpk(const float* __restrict__ ea,
                                                  const float* __restrict__ w1,
                                                  const float* __restrict__ b1,
                                                  const int* __restrict__ ei,
                                                  const int* __restrict__ src_off,
                                                  const int* __restrict__ dst_off,
                                                  const int* __restrict__ rs,
                                                  const int* __restrict__ rd,
                                                  unsigned int* __restrict__ apk,
                                                  int* __restrict__ s2d, int E){
  int idx = blockIdx.x * 256 + threadIdx.x;
  int e = idx >> 5, h2 = idx & 31;
  if (e >= E) return;
  int s = ei[e], d = ei[E + e];
  int ps = src_off[s] + rs[e];
  const float* eap = ea + (size_t)e * 5;
  float q0 = eap[0], q1 = eap[1], q2 = eap[2], q3 = eap[3], q4 = eap[4];
  int h = 2 * h2;
  float lo = b1[h]     + q0 * w1[h]       + q1 * w1[64 + h]     + q2 * w1[128 + h]
                       + q3 * w1[192 + h] + q4 * w1[256 + h];
  float hi = b1[h + 1] + q0 * w1[h + 1]   + q1 * w1[64 + h + 1] + q2 * w1[128 + h + 1]
                       + q3 * w1[192 + h + 1] + q4 * w1[256 + h + 1];
  apk[(size_t)ps * 32 + h2] = pk2(fmaxf(lo, 0.f), fmaxf(hi, 0.f));
  if (h2 == 0) s2d[ps] = dst_off[d] + rd[e];
}

// ---------- fused per-iteration kernel ----------
// 512 threads, 8 waves. Phase A: T = feat_chunk(16 nodes) @ M via MFMA,
// 64 pair-jobs over 8 waves (all 16 rows used). Phase B: per-node MFMA
// edge-GEMM (2 nodes/wave), msg stored packed f16 (o, o+16).
__global__ __launch_bounds__(512, 2) void kTA(const float* __restrict__ feat,
                                              const uint4* __restrict__ Mpk2,
                                              const int* __restrict__ s2d,
                                              const unsigned int* __restrict__ apk,
                                              const int* __restrict__ src_off,
                                              unsigned int* __restrict__ msg16,
                                              int N){
  __shared__ unsigned int Tp[CHUNK * 1024];   // 64 KB, [node][o*32 + swz(word)]
  __shared__ float bias_l[CHUNK][33];
  int tid = threadIdx.x;
  int c0 = blockIdx.x * CHUNK;
  int c1 = min(c0 + CHUNK, N);
  int nvalid = c1 - c0;
  int w = tid >> 6, l = tid & 63;
  int m = l & 15, q = l >> 4;

  // ---- phase A: 64 pair-jobs over 8 waves (+ bias on wave 7) ----
  {
    int nodeA = c0 + m;
    if (nodeA > c1 - 1) nodeA = c1 - 1;
    const float* fr = feat + (size_t)nodeA * 32 + q * 8;
    float4 fa = *(const float4*)fr;
    float4 fb = *(const float4*)(fr + 4);
    union { uint4 u; f16x8 h; } A;
    A.u.x = pk2(fa.x, fa.y); A.u.y = pk2(fa.z, fa.w);
    A.u.z = pk2(fb.x, fb.y); A.u.w = pk2(fb.z, fb.w);

#pragma unroll 4
    for (int jj2 = 0; jj2 < 8; jj2++){
      int job = w * 8 + jj2;
      int t = job >> 1, s = job & 1;
      int cE = 4 * t + s, cO = 4 * t + 2 + s;
      union { uint4 u; f16x8 h; } BE, BO;
      BE.u = Mpk2[cE * 64 + l];
      BO.u = Mpk2[cO * 64 + l];
      f32x4 z = {0.f, 0.f, 0.f, 0.f};
      f32x4 dE = __builtin_amdgcn_mfma_f32_16x16x32_f16(A.h, BE.h, z, 0, 0, 0);
      f32x4 dO = __builtin_amdgcn_mfma_f32_16x16x32_f16(A.h, BO.h, z, 0, 0, 0);
      int o = s * 16 + m;
      int sw = (((t >> 2) ^ (m & 7)) << 2) | (t & 3);
#pragma unroll
      for (int r = 0; r < 4; r++){
        int nn = q * 4 + r;
        if (nn < nvalid) Tp[nn * 1024 + o * 32 + sw] = pk2(dE[r], dO[r]);
      }
    }
    if (w == 7){   // bias row (job 64)
      union { uint4 u; f16x8 h; } BE, BO;
      BE.u = Mpk2[128 * 64 + l];
      BO.u = Mpk2[129 * 64 + l];
      f32x4 z = {0.f, 0.f, 0.f, 0.f};
      f32x4 dE = __builtin_amdgcn_mfma_f32_16x16x32_f16(A.h, BE.h, z, 0, 0, 0);
      f32x4 dO = __builtin_amdgcn_mfma_f32_16x16x32_f16(A.h, BO.h, z, 0, 0, 0);
#pragma unroll
      for (int r = 0; r < 4; r++){
        int nn = q * 4 + r;
        if (nn < nvalid){
          bias_l[nn][m]      = dE[r];
          bias_l[nn][16 + m] = dO[r];
        }
      }
    }
  }
  __syncthreads();

  // ---- phase B: per-node MFMA edge-GEMM (wave w handles nodes 2w, 2w+1) ----
  for (int un = 0; un < 2; un++){
    int u = w * 2 + un;
    if (u >= nvalid) continue;
    int su = src_off[c0 + u], eu = src_off[c0 + u + 1];
    if (su >= eu) continue;
    const uint4* tb = (const uint4*)(Tp + u * 1024);
    union { uint4 u4; f16x8 h; } B00, B01, B10, B11;
    B00.u4 = tb[m * 8 + (q ^ (m & 7))];
    B10.u4 = tb[m * 8 + ((4 + q) ^ (m & 7))];
    B01.u4 = tb[(16 + m) * 8 + (q ^ (m & 7))];
    B11.u4 = tb[(16 + m) * 8 + ((4 + q) ^ (m & 7))];
    float b0 = bias_l[u][m], b1 = bias_l[u][16 + m];
    for (int jt = su; jt < eu; jt += 16){
      union { uint4 u4; f16x8 h; } A0, A1;
      const uint4* arow = (const uint4*)(apk + (size_t)(jt + m) * 32);
      A0.u4 = arow[q];
      A1.u4 = arow[4 + q];
      f32x4 z = {0.f, 0.f, 0.f, 0.f};
      f32x4 D0 = __builtin_amdgcn_mfma_f32_16x16x32_f16(A0.h, B00.h, z, 0, 0, 0);
      D0 = __builtin_amdgcn_mfma_f32_16x16x32_f16(A1.h, B10.h, D0, 0, 0, 0);
      f32x4 D1 = __builtin_amdgcn_mfma_f32_16x16x32_f16(A0.h, B01.h, z, 0, 0, 0);
      D1 = __builtin_amdgcn_mfma_f32_16x16x32_f16(A1.h, B11.h, D1, 0, 0, 0);
#pragma unroll
      for (int r = 0; r < 4; r++){
        int e = jt + q * 4 + r;
        if (e < eu){
          msg16[(size_t)s2d[e] * 16 + m] = pk2(D0[r] + b0, D1[r] + b1);
        }
      }
    }
  }
}

// aggregate packed msg (dst-ordered) + conv bias + relu + GRU (packed-f16 dot2)
__global__ __launch_bounds__(256) void kB(const unsigned int* __restrict__ msg16,
                                          const int* __restrict__ dst_off,
                                          const float* __restrict__ deg,
                                          const float* __restrict__ feat_in,
                                          float* __restrict__ feat_out,
                                          float* __restrict__ out2,
                                          const float* __restrict__ Wih,
                                          const float* __restrict__ Whh,
                                          const float* __restrict__ bih,
                                          const float* __restrict__ bhh,
                                          const float* __restrict__ cbias, int N){
  __shared__ unsigned int wihpk[96][17], whhpk[96][17];
  __shared__ float bi[96], bh[96], cb[32];
  __shared__ unsigned int mshpk[8][17], hshpk[8][17];
  int tid = threadIdx.x;
  for (int k = tid; k < 96 * 16; k += 256){
    int g = k >> 4, q2 = k & 15;
    wihpk[g][q2] = pk2(Wih[g * 32 + 2 * q2], Wih[g * 32 + 2 * q2 + 1]);
    whhpk[g][q2] = pk2(Whh[g * 32 + 2 * q2], Whh[g * 32 + 2 * q2 + 1]);
  }
  if (tid < 96){ bi[tid] = bih[tid]; bh[tid] = bhh[tid]; }
  if (tid < 32) cb[tid] = cbias[tid];
  __syncthreads();
  int s = tid >> 5, o = tid & 31;
  unsigned int sel = (o < 16) ? pk2(1.f, 0.f) : pk2(0.f, 1.f);
  int w16 = o & 15;
  for (int g8 = 0; g8 < KBN / 8; g8++){
    int v = blockIdx.x * KBN + g8 * 8 + s;
    if (v < N){
      int lo = dst_off[v], hi = dst_off[v + 1];
      float h = feat_in[(size_t)v * 32 + o];
      float a0 = 0.f, a1 = 0.f, a2 = 0.f, a3 = 0.f;
      int k = lo;
      for (; k + 3 < hi; k += 4){
        a0 = dot2(msg16[(size_t)(k + 0) * 16 + w16], sel, a0);
        a1 = dot2(msg16[(size_t)(k + 1) * 16 + w16], sel, a1);
        a2 = dot2(msg16[(size_t)(k + 2) * 16 + w16], sel, a2);
        a3 = dot2(msg16[(size_t)(k + 3) * 16 + w16], sel, a3);
      }
      for (; k < hi; k++) a0 = dot2(msg16[(size_t)k * 16 + w16], sel, a0);
      float acc = (a0 + a1) + (a2 + a3);
      float m = fmaxf(acc / deg[v] + cb[o], 0.f);
      float m1 = __shfl_down(m, 1);
      float h1 = __shfl_down(h, 1);
      if (!(o & 1)){
        mshpk[s][o >> 1] = pk2(m, m1);
        hshpk[s][o >> 1] = pk2(h, h1);
      }
      float gr = bi[o], gz = bi[32 + o], gn = bi[64 + o];
      float hr = bh[o], hz = bh[32 + o], hn = bh[64 + o];
#pragma unroll
      for (int q2 = 0; q2 < 16; q2++){
        unsigned int mq = mshpk[s][q2], hq = hshpk[s][q2];
        gr = dot2(mq, wihpk[o][q2], gr);
        gz = dot2(mq, wihpk[32 + o][q2], gz);
        gn = dot2(mq, wihpk[64 + o][q2], gn);
        hr = dot2(hq, whhpk[o][q2], hr);
        hz = dot2(hq, whhpk[32 + o][q2], hz);
        hn = dot2(hq, whhpk[64 + o][q2], hn);
      }
      float r = 1.f / (1.f + expf(-(gr + hr)));
      float z = 1.f / (1.f + expf(-(gz + hz)));
      float n = tanhf(gn + r * hn);
      float val = (1.f - z) * n + z * h;
      feat_out[(size_t)v * 32 + o] = val;
      if (out2) out2[(size_t)v * 32 + o] = val;
    }
  }
}

// ---------- fused Set2Set ----------
__global__ __launch_bounds__(256) void kS2S(const float* __restrict__ feat,
                                            const int* __restrict__ boff,
                                            const float* __restrict__ Wih,
                                            const float* __restrict__ Whh,
                                            const float* __restrict__ bih,
                                            const float* __restrict__ bhh,
                                            float* __restrict__ e_buf,
                                            float* __restrict__ out){
  int b = blockIdx.x;
  __shared__ float WihL[128][65];
  __shared__ float WhhL[128][33];
  __shared__ float qs[64], hst[32], cst[32], garr[128];
  __shared__ float wred[4];
  __shared__ float part[8][33];
  int tid = threadIdx.x;
  for (int k = tid; k < 128 * 64; k += 256) WihL[k >> 6][k & 63] = Wih[k];
  for (int k = tid; k < 128 * 32; k += 256) WhhL[k >> 5][k & 31] = Whh[k];
  if (tid < 64) qs[tid] = 0.f;
  if (tid < 32){ hst[tid] = 0.f; cst[tid] = 0.f; }
  __syncthreads();
  int lo = boff[b], hi = boff[b + 1];
  int sub = tid >> 5, o = tid & 31;
  for (int step = 0; step < 3; step++){
    if (tid < 128){
      float acc = bih[tid] + bhh[tid];
#pragma unroll 8
      for (int j = 0; j < 64; j++) acc += qs[j] * WihL[tid][j];
#pragma unroll 8
      for (int j = 0; j < 32; j++) acc += hst[j] * WhhL[tid][j];
      garr[tid] = acc;
    }
    __syncthreads();
    if (tid < 32){
      float iv = 1.f / (1.f + expf(-garr[tid]));
      float fv = 1.f / (1.f + expf(-garr[32 + tid]));
      float gv = tanhf(garr[64 + tid]);
      float ov = 1.f / (1.f + expf(-garr[96 + tid]));
      float c = fv * cst[tid] + iv * gv;
      cst[tid] = c;
      float hv = ov * tanhf(c);
      hst[tid] = hv;
      qs[tid] = hv;
    }
    __syncthreads();
    float mx = -1e30f;
    for (int i = lo + tid; i < hi; i += 256){
      const float* fr = feat + (size_t)i * 32;
      float acc = 0.f;
#pragma unroll
      for (int c4 = 0; c4 < 8; c4++){
        float4 f = *(const float4*)(fr + c4 * 4);
        acc += f.x * hst[c4 * 4] + f.y * hst[c4 * 4 + 1]
             + f.z * hst[c4 * 4 + 2] + f.w * hst[c4 * 4 + 3];
      }
      e_buf[i] = acc;
      mx = fmaxf(mx, acc);
    }
#pragma unroll
    for (int d2 = 32; d2; d2 >>= 1) mx = fmaxf(mx, __shfl_xor(mx, d2, 64));
    if ((tid & 63) == 0) wred[tid >> 6] = mx;
    __syncthreads();
    mx = fmaxf(fmaxf(wred[0], wred[1]), fmaxf(wred[2], wred[3]));
    __syncthreads();
    float sm = 0.f;
    for (int i = lo + tid; i < hi; i += 256){
      float w2 = expf(e_buf[i] - mx);
      e_buf[i] = w2;
      sm += w2;
    }
#pragma unroll
    for (int d2 = 32; d2; d2 >>= 1) sm += __shfl_xor(sm, d2, 64);
    if ((tid & 63) == 0) wred[tid >> 6] = sm;
    __syncthreads();
    float denom = fmaxf(wred[0] + wred[1] + wred[2] + wred[3], 1e-30f);
    float a0 = 0.f, a1 = 0.f, a2 = 0.f, a3 = 0.f;
    int i = lo + sub;
    for (; i + 24 < hi; i += 32){
      a0 += e_buf[i]      * feat[(size_t)i * 32 + o];
      a1 += e_buf[i + 8]  * feat[(size_t)(i + 8) * 32 + o];
      a2 += e_buf[i + 16] * feat[(size_t)(i + 16) * 32 + o];
      a3 += e_buf[i + 24] * feat[(size_t)(i + 24) * 32 + o];
    }
    for (; i < hi; i += 8) a0 += e_buf[i] * feat[(size_t)i * 32 + o];
    part[sub][o] = (a0 + a1) + (a2 + a3);
    __syncthreads();
    if (tid < 32){
      float r2 = 0.f;
#pragma unroll
      for (int s2 = 0; s2 < 8; s2++) r2 += part[s2][tid];
      qs[32 + tid] = r2 / denom;
    }
    __syncthreads();
  }
  if (tid < 64) out[b * 64 + tid] = qs[tid];
}

// ---------- host ----------

extern "C" void kernel_launch(void* const* d_in, const int* in_sizes, int n_in,
                              void* d_out, int out_size, void* d_ws, size_t ws_size,
                              hipStream_t stream){
  (void)n_in; (void)out_size; (void)ws_size;
  const float* x        = (const float*)d_in[0];
  const int*   ei       = (const int*)  d_in[1];
  const float* eattr    = (const float*)d_in[2];
  const int*   batch    = (const int*)  d_in[3];
  const float* lin0_w   = (const float*)d_in[4];
  const float* lin0_b   = (const float*)d_in[5];
  const float* mlp_w1   = (const float*)d_in[6];
  const float* mlp_b1   = (const float*)d_in[7];
  const float* mlp_w2   = (const float*)d_in[8];
  const float* mlp_b2   = (const float*)d_in[9];
  const float* conv_b   = (const float*)d_in[10];
  const float* gru_wih  = (const float*)d_in[11];
  const float* gru_whh  = (const float*)d_in[12];
  const float* gru_bih  = (const float*)d_in[13];
  const float* gru_bhh  = (const float*)d_in[14];
  const float* lstm_wih = (const float*)d_in[15];
  const float* lstm_whh = (const float*)d_in[16];
  const float* lstm_bih = (const float*)d_in[17];
  const float* lstm_bhh = (const float*)d_in[18];

  int N = in_sizes[0] / NFEAT;
  int E = in_sizes[1] / 2;
  int NT = (N + 255) / 256;

  char* ws = (char*)d_ws;
  size_t off = 0;
  auto alloc = [&](size_t bytes) -> char* {
    char* p = ws + off;
    off = align_up(off + bytes, 256);
    return p;
  };

  float* feat0  = (float*)alloc((size_t)N * D * 4);
  float* feat1  = (float*)alloc((size_t)N * D * 4);
  unsigned int* msg16 = (unsigned int*)alloc((size_t)E * 16 * 4);
  unsigned int* Mpk2 = (unsigned int*)alloc((size_t)130 * 64 * 4 * 4);
  unsigned int* apk = (unsigned int*)alloc((size_t)E * 32 * 4 + 4096);  // +pad: A-frag over-read
  float* e_buf  = (float*)alloc((size_t)N * 4);
  float* deg    = (float*)alloc((size_t)N * 4);
  int* cnt_src  = (int*)alloc((size_t)N * CPAD * 4);
  int* cnt_dst  = (int*)alloc((size_t)N * CPAD * 4);
  int* rs       = (int*)alloc((size_t)E * 4);
  int* rd       = (int*)alloc((size_t)E * 4);
  int* src_off  = (int*)alloc((size_t)(N + 1) * 4);
  int* dst_off  = (int*)alloc((size_t)(N + 1) * 4);
  int* boff     = (int*)alloc((size_t)(NB + 1) * 4);
  int* bsum     = (int*)alloc((size_t)2 * NT * 4);
  int* s2d      = (int*)alloc((size_t)E * 4 + 256);   // +pad

  (void)hipMemsetAsync(cnt_src, 0, (size_t)N * CPAD * 4 * 2, stream);

  kBuildMpk2<<<(130 * 64 * 4 + 255) / 256, 256, 0, stream>>>(mlp_w2, mlp_b2, Mpk2);
  kLin0<<<(N * 32 + 255) / 256, 256, 0, stream>>>(x, lin0_w, lin0_b, feat0, N);
  kCountRank<<<(E + 255) / 256, 256, 0, stream>>>(ei, cnt_src, cnt_dst, rs, rd, E);
  {
    dim3 gA(NT, 2);
    kScanA<<<gA, 256, 0, stream>>>(cnt_src, cnt_dst, src_off, dst_off, bsum, deg, N, NT);
    kScanB<<<1, 256, 0, stream>>>(bsum, batch, boff, src_off, dst_off, N, NT, NB, E);
    kScanC<<<gA, 256, 0, stream>>>(src_off, dst_off, bsum, N, NT);
  }
  kEdgeMLPpk<<<((size_t)E * 32 + 255) / 256, 256, 0, stream>>>(eattr, mlp_w1, mlp_b1,
                                                               ei, src_off, dst_off,
                                                               rs, rd, apk, s2d, E);

  int blocksTA = (N + CHUNK - 1) / CHUNK;
  float* fcur = feat0;
  float* fnext = feat1;
  for (int t = 0; t < 3; t++){
    kTA<<<blocksTA, 512, 0, stream>>>(fcur, (const uint4*)Mpk2, s2d, apk,
                                      src_off, msg16, N);
    float* out2 = (t == 2) ? ((float*)d_out + NB * 64) : nullptr;
    kB<<<(N + KBN - 1) / KBN, 256, 0, stream>>>(msg16, dst_off, deg, fcur, fnext, out2,
                                                gru_wih, gru_whh, gru_bih, gru_bhh,
                                                conv_b, N);
    float* tmp = fcur; fcur = fnext; fnext = tmp;
  }

  kS2S<<<NB, 256, 0, stream>>>(fcur, boff, lstm_wih, lstm_whh, lstm_bih, lstm_bhh,
                               e_buf, (float*)d_out);
}